// Round 4
// baseline (340.843 us; speedup 1.0000x reference)
//
#include <hip/hip_runtime.h>
#include <math.h>

#define DIM   2048
#define NEXP  64
#define NGRP  8
#define GSIZE 8
#define TOPK  8
#define TOPKG 4

#define NKS   8              // K-slices per gemm block (one per wave)
#define KSL   (DIM / NKS)    // 256 k per slice
#define SMSTR 548            // 8*68+4 floats: bank-rotating k-slice stride

// margin thresholds (fp32 score scale). f16-split GEMM logit error:
// split residual ~2^-21-scale + fp32 MFMA accum ~6e-7 -> score 5-sigma
// ~1e-6. TAU ~20x that. Expected flag rate ~1-1.5%.
#define TAU_E 2e-5f
#define TAU_G 4e-5f
#define NEG_INF (-3.4e38f)
#define WLOFF 16
#define WT_OFF (1 << 18)     // Wf at d_ws + 256 KB (512 KB of packed B-frags)
#define SG_OFF (1 << 20)     // score table at d_ws + 1 MB (4 MB)

typedef __attribute__((ext_vector_type(8)))  _Float16 f16x8;  // 8 f16 (4 VGPR)
typedef __attribute__((ext_vector_type(16))) float    f32x16; // 32x32 C/D

// ---- kernel 0: pack W into B-fragment layout (hi/lo f16) + zero worklist --
// B-frag for mfma_f32_32x32x16_f16: B[k][n], n = lane&31, k = (lane>>5)*8+j.
// Wf element index: (((h*2 + n2)*128 + kc)*64 + lane)*8 + j   (ushorts)
__global__ __launch_bounds__(256) void prep_kernel(
    const float* __restrict__ W, unsigned short* __restrict__ Wf,
    int* __restrict__ wl)
{
    const int g = blockIdx.x * 256 + threadIdx.x;   // 0..131071
    const int e = g >> 11, k = g & 2047;
    const float w = W[g];                            // W[e][k], coalesced
    const _Float16 hi = (_Float16)w;                 // RNE
    const _Float16 lo = (_Float16)(w - (float)hi);   // exact residual, RNE
    const int n2 = e >> 5, lcol = e & 31;
    const int kc = k >> 4, khalf = (k >> 3) & 1, j = k & 7;
    const int lane = (khalf << 5) | lcol;
    Wf[((((0 * 2 + n2) * 128 + kc) << 6) + lane) * 8 + j] =
        __builtin_bit_cast(unsigned short, hi);
    Wf[((((1 * 2 + n2) * 128 + kc) << 6) + lane) * 8 + j] =
        __builtin_bit_cast(unsigned short, lo);
    if (g < WLOFF) wl[g] = 0;
}

// ---- kernel 1: f16-split MFMA GEMM + merge + sigmoid -> score table -------
// 512 threads = 8 waves, 32 tokens/block, grid 512 (2 blocks/CU for barrier
// decoupling). Wave ks owns K-slice [256ks, 256ks+256), R0-style compiler-
// scheduled prefetch loads. Merge 8 partials in LDS (4 rounds x 8 tokens),
// fused bias+sigmoid, write score table sSg[token][64] (wv + bias).
__global__ __launch_bounds__(512, 2) void gemm_kernel(
    const float* __restrict__ x,
    const unsigned short* __restrict__ Wf,
    const float* __restrict__ b,
    const float* __restrict__ bias,
    float* __restrict__ sSg)
{
    __shared__ float sM[NKS * SMSTR];    // 17.5 KB merge buffer

    const int tid  = threadIdx.x;
    const int ks   = tid >> 6;           // wave = K-slice 0..7
    const int lane = tid & 63;
    const int tok0 = blockIdx.x * 32;
    const int l31  = lane & 31, lh = lane >> 5;

    // A operand: A[row = lane&31][k-run = (lane>>5)*8 + j]
    const float* xr = x + (size_t)(tok0 + l31) * DIM + ks * KSL + lh * 8;
    const f16x8* Wfv = (const f16x8*)Wf;   // 16 B per element

    f32x16 acc0, acc1;
#pragma unroll
    for (int z = 0; z < 16; ++z) { acc0[z] = 0.f; acc1[z] = 0.f; }

    float4 p0 = *(const float4*)(xr + 0);
    float4 p1 = *(const float4*)(xr + 4);
    float4 p2 = *(const float4*)(xr + 16);
    float4 p3 = *(const float4*)(xr + 20);

#pragma unroll 1
    for (int i = 0; i < 8; ++i) {        // 2 chunks of K=16 per iteration
        const float4 c00 = p0, c01 = p1, c10 = p2, c11 = p3;
        if (i + 1 < 8) {
            p0 = *(const float4*)(xr + 32 * (i + 1) + 0);
            p1 = *(const float4*)(xr + 32 * (i + 1) + 4);
            p2 = *(const float4*)(xr + 32 * (i + 1) + 16);
            p3 = *(const float4*)(xr + 32 * (i + 1) + 20);
        }
        const int kc0 = ks * 16 + 2 * i;

#pragma unroll
        for (int c = 0; c < 2; ++c) {
            const int kc = kc0 + c;
            const float4 qa = c ? c10 : c00;
            const float4 qb = c ? c11 : c01;
            const float xv[8] = {qa.x, qa.y, qa.z, qa.w, qb.x, qb.y, qb.z, qb.w};
            f16x8 ah, al;
#pragma unroll
            for (int j = 0; j < 8; j += 2) {
                const auto h2 = __builtin_amdgcn_cvt_pkrtz(xv[j], xv[j + 1]);
                const auto l2 = __builtin_amdgcn_cvt_pkrtz(xv[j]     - (float)h2.x,
                                                           xv[j + 1] - (float)h2.y);
                ah[j] = h2.x; ah[j + 1] = h2.y;
                al[j] = l2.x; al[j + 1] = l2.y;
            }
            // B frags (pre-packed, L2-hot): idx = ((h*2+nt)*128 + kc)*64 + lane
            const f16x8 bh0 = Wfv[((0 * 2 + 0) * 128 + kc) * 64 + lane];
            const f16x8 bh1 = Wfv[((0 * 2 + 1) * 128 + kc) * 64 + lane];
            const f16x8 bl0 = Wfv[((1 * 2 + 0) * 128 + kc) * 64 + lane];
            const f16x8 bl1 = Wfv[((1 * 2 + 1) * 128 + kc) * 64 + lane];

            acc0 = __builtin_amdgcn_mfma_f32_32x32x16_f16(ah, bh0, acc0, 0, 0, 0);
            acc0 = __builtin_amdgcn_mfma_f32_32x32x16_f16(ah, bl0, acc0, 0, 0, 0);
            acc0 = __builtin_amdgcn_mfma_f32_32x32x16_f16(al, bh0, acc0, 0, 0, 0);
            acc1 = __builtin_amdgcn_mfma_f32_32x32x16_f16(ah, bh1, acc1, 0, 0, 0);
            acc1 = __builtin_amdgcn_mfma_f32_32x32x16_f16(ah, bl1, acc1, 0, 0, 0);
            acc1 = __builtin_amdgcn_mfma_f32_32x32x16_f16(al, bh1, acc1, 0, 0, 0);
        }
    }

    // ---- merge 8 K-slice partials (4 rounds x 8 tokens), fused sigmoid ----
    // C/D layout (m74/m101-verified): col = lane&31,
    // row = (reg&3) + 8*(reg>>2) + 4*(lane>>5); reg = 4r+jj -> row = 8r+jj+4lh
#pragma unroll
    for (int r = 0; r < 4; ++r) {
#pragma unroll
        for (int jj = 0; jj < 4; ++jj) {
            const int t8 = jj + 4 * lh;                // row-in-round 0..7
            sM[ks * SMSTR + t8 * 68 + l31]      = acc0[4 * r + jj];
            sM[ks * SMSTR + t8 * 68 + l31 + 32] = acc1[4 * r + jj];
        }
        __syncthreads();
        {
            const int row = tid >> 6;                  // 0..7
            const int e   = tid & 63;
            float sum = 0.f;
#pragma unroll
            for (int s = 0; s < NKS; ++s)
                sum += sM[s * SMSTR + row * 68 + e];   // ordered, deterministic
            const float logit = sum + b[e];
            const float wv = 1.0f / (1.0f + expf(-logit));
            sSg[(size_t)(tok0 + 8 * r + row) * NEXP + e] = wv + bias[e];
        }
        __syncthreads();
    }
}

// ---- kernel 2: routing + margin flagging from score table ------------------
// 128 tokens/block staged in LDS [128][65] (conflict-free reads), one thread
// per token runs the serial top-k + margin logic (identical to prior rounds).
__global__ __launch_bounds__(256) void route_kernel(
    const float* __restrict__ sSg,
    const float* __restrict__ bias,
    float* __restrict__ out_w,
    float* __restrict__ out_i,
    int* __restrict__ wl)
{
    __shared__ float sT[128][65];        // 33.3 KB

    const int tid  = threadIdx.x;
    const int tok0 = blockIdx.x * 128;

    // stage: 128 tokens x 64 scores, coalesced float4 loads, scalar LDS stores
    const float4* S4 = (const float4*)sSg + (size_t)tok0 * (NEXP / 4);
#pragma unroll
    for (int q = 0; q < 8; ++q) {
        const int idx = q * 256 + tid;           // 0..2047 float4s
        const int tk  = idx >> 4, c4 = idx & 15;
        const float4 v = S4[idx];
        sT[tk][c4 * 4 + 0] = v.x;
        sT[tk][c4 * 4 + 1] = v.y;
        sT[tk][c4 * 4 + 2] = v.z;
        sT[tk][c4 * 4 + 3] = v.w;
    }
    __syncthreads();

    if (tid < 128) {
        const int t = tid;

        float gs[NGRP];
#pragma unroll
        for (int g = 0; g < NGRP; ++g) {
            float m1 = NEG_INF, m2 = NEG_INF;
#pragma unroll
            for (int j = 0; j < GSIZE; ++j) {
                const float v = sT[t][g * GSIZE + j];
                if (v > m1) { m2 = m1; m1 = v; }
                else if (v > m2) { m2 = v; }
            }
            gs[g] = m1 + m2;
        }

        unsigned gmask = 0u;
        float g4val = NEG_INF;
        for (int rr = 0; rr < TOPKG; ++rr) {
            float best = NEG_INF; int bi = 0;
#pragma unroll
            for (int g = 0; g < NGRP; ++g) {
                const float v = ((gmask >> g) & 1u) ? NEG_INF : gs[g];
                if (v > best) { best = v; bi = g; }
            }
            gmask |= 1u << bi;
            g4val = best;
        }
        float m5 = NEG_INF;
#pragma unroll
        for (int g = 0; g < NGRP; ++g)
            if (!((gmask >> g) & 1u) && gs[g] > m5) m5 = gs[g];
        const float margin_g = g4val - m5;

        unsigned long long chosen = 0ull;
        const size_t obase = (size_t)(tok0 + t) * TOPK;
        float vals[TOPK + 1];
        for (int rr = 0; rr < TOPK + 1; ++rr) {
            float best = NEG_INF; int bi = 0;
            for (int e = 0; e < NEXP; ++e) {
                float v = ((gmask >> (e >> 3)) & 1u) ? sT[t][e] : 0.0f;
                if ((chosen >> e) & 1ull) v = NEG_INF;
                if (v > best) { best = v; bi = e; }
            }
            vals[rr] = best;
            if (rr < TOPK) {
                chosen |= 1ull << (unsigned)bi;
                out_w[obase + rr] = ((gmask >> (bi >> 3)) & 1u)
                                  ? (sT[t][bi] - bias[bi]) : 0.0f;
                out_i[obase + rr] = (float)bi;
            }
        }
        float margin_e = 1e30f;
#pragma unroll
        for (int rr = 0; rr < TOPK; ++rr) {
            const float d = vals[rr] - vals[rr + 1];
            if (d < margin_e) margin_e = d;
        }

        if (margin_g < TAU_G || margin_e < TAU_E) {
            const int slot = atomicAdd(wl, 1);
            wl[WLOFF + slot] = tok0 + t;
        }
    }
}

// ---- kernel 3: fp64 exact fixup, ONE WAVE PER TOKEN, lane = expert --------
// W row per lane streamed from L2 (512 KB, resident); x broadcast per lane.
// Total W traffic = count x 512 KB from L2 (not per-token HBM re-reads).
__global__ __launch_bounds__(256) void gate_fix_kernel(
    const float* __restrict__ x,
    const float* __restrict__ W,
    const float* __restrict__ b,
    const float* __restrict__ bias,
    float* __restrict__ out_w,
    float* __restrict__ out_i,
    const int* __restrict__ wl)
{
    const int count = wl[0];

    __shared__ float sS2[4][NEXP];
    __shared__ float sW2[4][NEXP];

    const int tid  = threadIdx.x;
    const int wv_  = tid >> 6;           // wave in block 0..3
    const int lane = tid & 63;           // = expert
    const int gw   = blockIdx.x * 4 + wv_;

    const float4* Wr = (const float4*)(W + (size_t)lane * DIM);

    for (int widx = gw; widx < count; widx += (int)gridDim.x * 4) {
        const int tok = wl[WLOFF + widx];
        const float4* xr = (const float4*)(x + (size_t)tok * DIM);

        double a0 = 0., a1 = 0., a2 = 0., a3 = 0.;
#pragma unroll 4
        for (int c = 0; c < DIM / 16; ++c) {     // 4 chains for ILP
            const float4 x0 = xr[4 * c + 0], w0 = Wr[4 * c + 0];
            const float4 x1 = xr[4 * c + 1], w1 = Wr[4 * c + 1];
            const float4 x2 = xr[4 * c + 2], w2 = Wr[4 * c + 2];
            const float4 x3 = xr[4 * c + 3], w3 = Wr[4 * c + 3];
            a0 = fma((double)x0.x, (double)w0.x, a0);
            a0 = fma((double)x0.y, (double)w0.y, a0);
            a0 = fma((double)x0.z, (double)w0.z, a0);
            a0 = fma((double)x0.w, (double)w0.w, a0);
            a1 = fma((double)x1.x, (double)w1.x, a1);
            a1 = fma((double)x1.y, (double)w1.y, a1);
            a1 = fma((double)x1.z, (double)w1.z, a1);
            a1 = fma((double)x1.w, (double)w1.w, a1);
            a2 = fma((double)x2.x, (double)w2.x, a2);
            a2 = fma((double)x2.y, (double)w2.y, a2);
            a2 = fma((double)x2.z, (double)w2.z, a2);
            a2 = fma((double)x2.w, (double)w2.w, a2);
            a3 = fma((double)x3.x, (double)w3.x, a3);
            a3 = fma((double)x3.y, (double)w3.y, a3);
            a3 = fma((double)x3.z, (double)w3.z, a3);
            a3 = fma((double)x3.w, (double)w3.w, a3);
        }
        const double logit = ((a0 + a1) + (a2 + a3)) + (double)b[lane];
        const float wvv = (float)(1.0 / (1.0 + exp(-logit)));
        sW2[wv_][lane] = wvv;
        sS2[wv_][lane] = wvv + bias[lane];
        asm volatile("s_waitcnt lgkmcnt(0)" ::: "memory");
        __builtin_amdgcn_wave_barrier();

        // redundant-uniform routing across all 64 lanes (wave-lockstep)
        float gsv[NGRP];
#pragma unroll
        for (int g = 0; g < NGRP; ++g) {
            float m1 = NEG_INF, m2 = NEG_INF;
#pragma unroll
            for (int j = 0; j < GSIZE; ++j) {
                const float v = sS2[wv_][g * GSIZE + j];
                if (v > m1) { m2 = m1; m1 = v; }
                else if (v > m2) { m2 = v; }
            }
            gsv[g] = m1 + m2;
        }
        unsigned gmask = 0u;
        for (int rr = 0; rr < TOPKG; ++rr) {
            float best = NEG_INF; int bi = 0;
#pragma unroll
            for (int g = 0; g < NGRP; ++g) {
                const float v = ((gmask >> g) & 1u) ? NEG_INF : gsv[g];
                if (v > best) { best = v; bi = g; }
            }
            gmask |= 1u << bi;
        }
        unsigned long long chosen = 0ull;
        float rw[TOPK]; int ri[TOPK];
        for (int rr = 0; rr < TOPK; ++rr) {
            float best = NEG_INF; int bi = 0;
            for (int e2 = 0; e2 < NEXP; ++e2) {
                float v = ((gmask >> (e2 >> 3)) & 1u) ? sS2[wv_][e2] : 0.0f;
                if ((chosen >> e2) & 1ull) v = NEG_INF;
                if (v > best) { best = v; bi = e2; }
            }
            chosen |= 1ull << (unsigned)bi;
            rw[rr] = ((gmask >> (bi >> 3)) & 1u) ? sW2[wv_][bi] : 0.0f;
            ri[rr] = bi;
        }
        if (lane == 0) {
            const size_t obase = (size_t)tok * TOPK;
#pragma unroll
            for (int rr = 0; rr < TOPK; ++rr) {
                out_w[obase + rr] = rw[rr];
                out_i[obase + rr] = (float)ri[rr];
            }
        }
        __builtin_amdgcn_wave_barrier();   // keep sS2 stable until loop back
    }
}

extern "C" void kernel_launch(void* const* d_in, const int* in_sizes, int n_in,
                              void* d_out, int out_size, void* d_ws, size_t ws_size,
                              hipStream_t stream) {
    const float* x    = (const float*)d_in[0];
    const float* W    = (const float*)d_in[1];
    const float* b    = (const float*)d_in[2];
    const float* bias = (const float*)d_in[3];

    const int n = in_sizes[0] / DIM;   // 16384 tokens
    float* out_w = (float*)d_out;
    float* out_i = out_w + (size_t)n * TOPK;
    int*   wl    = (int*)d_ws;
    unsigned short* Wf = (unsigned short*)((char*)d_ws + WT_OFF);
    float* sSg   = (float*)((char*)d_ws + SG_OFF);

    prep_kernel<<<dim3((NEXP * DIM) / 256), dim3(256), 0, stream>>>(W, Wf, wl);
    gemm_kernel<<<dim3(n / 32), dim3(512), 0, stream>>>(x, Wf, b, bias, sSg);
    route_kernel<<<dim3(n / 128), dim3(256), 0, stream>>>(
        sSg, bias, out_w, out_i, wl);
    gate_fix_kernel<<<dim3(256), dim3(256), 0, stream>>>(
        x, W, b, bias, out_w, out_i, wl);
}

// Round 5
// 308.759 us; speedup vs baseline: 1.1039x; 1.1039x over previous
//
#include <hip/hip_runtime.h>
#include <math.h>

#define DIM   2048
#define NEXP  64
#define NGRP  8
#define GSIZE 8
#define TOPK  8
#define TOPKG 4

#define NKS   8              // K-slices per gemm block (one per wave)
#define KSL   (DIM / NKS)    // 256 k per slice
#define SMSTR 548            // 8*68+4 floats: bank-rotating k-slice stride

// margin thresholds (fp32 score scale). f16-split GEMM logit error:
// split residual + fp32 MFMA accum -> score 5-sigma ~1e-6. TAU ~20x that.
#define TAU_E 2e-5f
#define TAU_G 4e-5f
#define NEG_INF (-3.4e38f)
#define WLOFF  16
#define WT_OFF  (1 << 18)        // Wf (packed B-frags, 512 KB) at +256 KB
#define WT2_OFF (3 << 18)        // Wt (transposed fp32 W, 512 KB) at +768 KB
#define SG_OFF  (1 << 21)        // score table (4 MB) at +2 MB

typedef __attribute__((ext_vector_type(8)))  _Float16 f16x8;  // 8 f16 (4 VGPR)
typedef __attribute__((ext_vector_type(16))) float    f32x16; // 32x32 C/D

#define SB() __builtin_amdgcn_sched_barrier(0)

// ---- kernel 0: pack W into B-frag layout (hi/lo f16) + transposed fp32 ----
// B-frag for mfma_f32_32x32x16_f16: B[k][n], n = lane&31, k = (lane>>5)*8+j.
// Wf element index: (((h*2 + n2)*128 + kc)*64 + lane)*8 + j   (ushorts)
// Wt layout (for coalesced fix): float[((k>>2)*64 + e)*4 + (k&3)]
__global__ __launch_bounds__(256) void prep_kernel(
    const float* __restrict__ W, unsigned short* __restrict__ Wf,
    float* __restrict__ Wt, int* __restrict__ wl)
{
    const int g = blockIdx.x * 256 + threadIdx.x;   // 0..131071
    const int e = g >> 11, k = g & 2047;
    const float w = W[g];                            // W[e][k], coalesced
    const _Float16 hi = (_Float16)w;                 // RNE
    const _Float16 lo = (_Float16)(w - (float)hi);   // exact residual, RNE
    const int n2 = e >> 5, lcol = e & 31;
    const int kc = k >> 4, khalf = (k >> 3) & 1, j = k & 7;
    const int lane = (khalf << 5) | lcol;
    Wf[((((0 * 2 + n2) * 128 + kc) << 6) + lane) * 8 + j] =
        __builtin_bit_cast(unsigned short, hi);
    Wf[((((1 * 2 + n2) * 128 + kc) << 6) + lane) * 8 + j] =
        __builtin_bit_cast(unsigned short, lo);
    Wt[(((k >> 2) * 64 + e) << 2) + (k & 3)] = w;
    if (g < WLOFF) wl[g] = 0;
}

// ---- kernel 1: f16-split MFMA GEMM + merge + sigmoid -> score table -------
// Homogeneous prefetch pipeline: per wave, ONE in-order VMEM stream (4 B-frag
// + 2 x loads per K-step), 2-slot register ring, fully unrolled 16 steps,
// CONSUME(t) then ISSUE(t+2), sched_barrier(0) pinned. Compiler's auto-wait
// becomes counted vmcnt(6): the next step's 6 loads are NEVER drained (the
// R0-R3 wall was vmcnt drains from mixed-use streams / per-step barriers).
// No barriers in the K-loop; waves fully independent until the merge.
__global__ __launch_bounds__(512, 2) void gemm_kernel(
    const float* __restrict__ x,
    const unsigned short* __restrict__ Wf,
    const float* __restrict__ b,
    const float* __restrict__ bias,
    float* __restrict__ sSg)
{
    __shared__ float sM[NKS * SMSTR];    // 17.5 KB merge buffer

    const int tid  = threadIdx.x;
    const int ks   = tid >> 6;           // wave = K-slice 0..7
    const int lane = tid & 63;
    const int tok0 = blockIdx.x * 32;
    const int l31  = lane & 31, lh = lane >> 5;

    // A operand: A[row = lane&31][k-run = (lane>>5)*8 + j]
    const float* xr = x + (size_t)(tok0 + l31) * DIM + ks * KSL + lh * 8;
    const f16x8* Wfv = (const f16x8*)Wf;   // 16 B per element

    f32x16 acc0, acc1;
#pragma unroll
    for (int z = 0; z < 16; ++z) { acc0[z] = 0.f; acc1[z] = 0.f; }

    f16x8  Bq[2][4];
    float4 Xq[2][2];

#define ISSUE(t) do {                                                         \
        const int kc_ = ks * 16 + (t);                                        \
        Bq[(t) & 1][0] = Wfv[((0 * 2 + 0) * 128 + kc_) * 64 + lane];          \
        Bq[(t) & 1][1] = Wfv[((0 * 2 + 1) * 128 + kc_) * 64 + lane];          \
        Bq[(t) & 1][2] = Wfv[((1 * 2 + 0) * 128 + kc_) * 64 + lane];          \
        Bq[(t) & 1][3] = Wfv[((1 * 2 + 1) * 128 + kc_) * 64 + lane];          \
        Xq[(t) & 1][0] = *(const float4*)(xr + 16 * (t));                     \
        Xq[(t) & 1][1] = *(const float4*)(xr + 16 * (t) + 4);                 \
    } while (0)

    ISSUE(0); SB();
    ISSUE(1); SB();

#pragma unroll
    for (int t = 0; t < 16; ++t) {
        // CONSUME(t): auto-wait = counted vmcnt (next step's loads stay out)
        {
            const float4 qa = Xq[t & 1][0], qb = Xq[t & 1][1];
            const float xv[8] = {qa.x, qa.y, qa.z, qa.w, qb.x, qb.y, qb.z, qb.w};
            f16x8 ah, al;
#pragma unroll
            for (int j = 0; j < 8; j += 2) {
                const auto h2 = __builtin_amdgcn_cvt_pkrtz(xv[j], xv[j + 1]);
                const auto l2 = __builtin_amdgcn_cvt_pkrtz(xv[j]     - (float)h2.x,
                                                           xv[j + 1] - (float)h2.y);
                ah[j] = h2.x; ah[j + 1] = h2.y;
                al[j] = l2.x; al[j + 1] = l2.y;
            }
            acc0 = __builtin_amdgcn_mfma_f32_32x32x16_f16(ah, Bq[t & 1][0], acc0, 0, 0, 0);
            acc0 = __builtin_amdgcn_mfma_f32_32x32x16_f16(ah, Bq[t & 1][2], acc0, 0, 0, 0);
            acc0 = __builtin_amdgcn_mfma_f32_32x32x16_f16(al, Bq[t & 1][0], acc0, 0, 0, 0);
            acc1 = __builtin_amdgcn_mfma_f32_32x32x16_f16(ah, Bq[t & 1][1], acc1, 0, 0, 0);
            acc1 = __builtin_amdgcn_mfma_f32_32x32x16_f16(ah, Bq[t & 1][3], acc1, 0, 0, 0);
            acc1 = __builtin_amdgcn_mfma_f32_32x32x16_f16(al, Bq[t & 1][1], acc1, 0, 0, 0);
        }
        SB();
        if (t + 2 < 16) { ISSUE(t + 2); SB(); }
    }
#undef ISSUE

    // ---- merge 8 K-slice partials (4 rounds x 8 tokens), fused sigmoid ----
    // C/D layout (m74/m101-verified): col = lane&31,
    // row = (reg&3) + 8*(reg>>2) + 4*(lane>>5); reg = 4r+jj -> row = 8r+jj+4lh
#pragma unroll
    for (int r = 0; r < 4; ++r) {
#pragma unroll
        for (int jj = 0; jj < 4; ++jj) {
            const int t8 = jj + 4 * lh;                // row-in-round 0..7
            sM[ks * SMSTR + t8 * 68 + l31]      = acc0[4 * r + jj];
            sM[ks * SMSTR + t8 * 68 + l31 + 32] = acc1[4 * r + jj];
        }
        __syncthreads();
        {
            const int row = tid >> 6;                  // 0..7
            const int e   = tid & 63;
            float sum = 0.f;
#pragma unroll
            for (int s = 0; s < NKS; ++s)
                sum += sM[s * SMSTR + row * 68 + e];   // ordered, deterministic
            const float logit = sum + b[e];
            const float wv = 1.0f / (1.0f + expf(-logit));
            sSg[(size_t)(tok0 + 8 * r + row) * NEXP + e] = wv + bias[e];
        }
        __syncthreads();
    }
}

// ---- kernel 2: routing + margin flagging from score table ------------------
__global__ __launch_bounds__(256) void route_kernel(
    const float* __restrict__ sSg,
    const float* __restrict__ bias,
    float* __restrict__ out_w,
    float* __restrict__ out_i,
    int* __restrict__ wl)
{
    __shared__ float sT[128][65];        // 33.3 KB

    const int tid  = threadIdx.x;
    const int tok0 = blockIdx.x * 128;

    const float4* S4 = (const float4*)sSg + (size_t)tok0 * (NEXP / 4);
#pragma unroll
    for (int q = 0; q < 8; ++q) {
        const int idx = q * 256 + tid;           // 0..2047 float4s
        const int tk  = idx >> 4, c4 = idx & 15;
        const float4 v = S4[idx];
        sT[tk][c4 * 4 + 0] = v.x;
        sT[tk][c4 * 4 + 1] = v.y;
        sT[tk][c4 * 4 + 2] = v.z;
        sT[tk][c4 * 4 + 3] = v.w;
    }
    __syncthreads();

    if (tid < 128) {
        const int t = tid;

        float gs[NGRP];
#pragma unroll
        for (int g = 0; g < NGRP; ++g) {
            float m1 = NEG_INF, m2 = NEG_INF;
#pragma unroll
            for (int j = 0; j < GSIZE; ++j) {
                const float v = sT[t][g * GSIZE + j];
                if (v > m1) { m2 = m1; m1 = v; }
                else if (v > m2) { m2 = v; }
            }
            gs[g] = m1 + m2;
        }

        unsigned gmask = 0u;
        float g4val = NEG_INF;
        for (int rr = 0; rr < TOPKG; ++rr) {
            float best = NEG_INF; int bi = 0;
#pragma unroll
            for (int g = 0; g < NGRP; ++g) {
                const float v = ((gmask >> g) & 1u) ? NEG_INF : gs[g];
                if (v > best) { best = v; bi = g; }
            }
            gmask |= 1u << bi;
            g4val = best;
        }
        float m5 = NEG_INF;
#pragma unroll
        for (int g = 0; g < NGRP; ++g)
            if (!((gmask >> g) & 1u) && gs[g] > m5) m5 = gs[g];
        const float margin_g = g4val - m5;

        unsigned long long chosen = 0ull;
        const size_t obase = (size_t)(tok0 + t) * TOPK;
        float vals[TOPK + 1];
        for (int rr = 0; rr < TOPK + 1; ++rr) {
            float best = NEG_INF; int bi = 0;
            for (int e = 0; e < NEXP; ++e) {
                float v = ((gmask >> (e >> 3)) & 1u) ? sT[t][e] : 0.0f;
                if ((chosen >> e) & 1ull) v = NEG_INF;
                if (v > best) { best = v; bi = e; }
            }
            vals[rr] = best;
            if (rr < TOPK) {
                chosen |= 1ull << (unsigned)bi;
                out_w[obase + rr] = ((gmask >> (bi >> 3)) & 1u)
                                  ? (sT[t][bi] - bias[bi]) : 0.0f;
                out_i[obase + rr] = (float)bi;
            }
        }
        float margin_e = 1e30f;
#pragma unroll
        for (int rr = 0; rr < TOPK; ++rr) {
            const float d = vals[rr] - vals[rr + 1];
            if (d < margin_e) margin_e = d;
        }

        if (margin_g < TAU_G || margin_e < TAU_E) {
            const int slot = atomicAdd(wl, 1);
            wl[WLOFF + slot] = tok0 + t;
        }
    }
}

// ---- kernel 3: fp64 exact fixup, wave per token, COALESCED via Wt ---------
// lane = expert; Wt4[k4*64 + lane] -> 64 lanes x 16 B = 1 KB contiguous per
// instruction (streaming, L2-friendly); x row is wave-uniform (1 line/load).
__global__ __launch_bounds__(256) void gate_fix_kernel(
    const float* __restrict__ x,
    const float* __restrict__ Wt,
    const float* __restrict__ b,
    const float* __restrict__ bias,
    float* __restrict__ out_w,
    float* __restrict__ out_i,
    const int* __restrict__ wl)
{
    const int count = wl[0];

    __shared__ float sS2[4][NEXP];
    __shared__ float sW2[4][NEXP];

    const int tid  = threadIdx.x;
    const int wv_  = tid >> 6;           // wave in block 0..3
    const int lane = tid & 63;           // = expert
    const int gw   = blockIdx.x * 4 + wv_;

    const float4* Wt4 = (const float4*)Wt;

    for (int widx = gw; widx < count; widx += (int)gridDim.x * 4) {
        const int tok = wl[WLOFF + widx];
        const float4* xr4 = (const float4*)(x + (size_t)tok * DIM);

        double a0 = 0., a1 = 0., a2 = 0., a3 = 0.;
#pragma unroll 4
        for (int k4 = 0; k4 < DIM / 4; ++k4) {
            const float4 wt = Wt4[(size_t)k4 * 64 + lane];
            const float4 xv = xr4[k4];
            a0 = fma((double)xv.x, (double)wt.x, a0);
            a1 = fma((double)xv.y, (double)wt.y, a1);
            a2 = fma((double)xv.z, (double)wt.z, a2);
            a3 = fma((double)xv.w, (double)wt.w, a3);
        }
        const double logit = ((a0 + a1) + (a2 + a3)) + (double)b[lane];
        const float wvv = (float)(1.0 / (1.0 + exp(-logit)));
        sW2[wv_][lane] = wvv;
        sS2[wv_][lane] = wvv + bias[lane];
        asm volatile("s_waitcnt lgkmcnt(0)" ::: "memory");
        __builtin_amdgcn_wave_barrier();

        // redundant-uniform routing across all 64 lanes (wave-lockstep)
        float gsv[NGRP];
#pragma unroll
        for (int g = 0; g < NGRP; ++g) {
            float m1 = NEG_INF, m2 = NEG_INF;
#pragma unroll
            for (int j = 0; j < GSIZE; ++j) {
                const float v = sS2[wv_][g * GSIZE + j];
                if (v > m1) { m2 = m1; m1 = v; }
                else if (v > m2) { m2 = v; }
            }
            gsv[g] = m1 + m2;
        }
        unsigned gmask = 0u;
        for (int rr = 0; rr < TOPKG; ++rr) {
            float best = NEG_INF; int bi = 0;
#pragma unroll
            for (int g = 0; g < NGRP; ++g) {
                const float v = ((gmask >> g) & 1u) ? NEG_INF : gsv[g];
                if (v > best) { best = v; bi = g; }
            }
            gmask |= 1u << bi;
        }
        unsigned long long chosen = 0ull;
        float rw[TOPK]; int ri[TOPK];
        for (int rr = 0; rr < TOPK; ++rr) {
            float best = NEG_INF; int bi = 0;
            for (int e2 = 0; e2 < NEXP; ++e2) {
                float v = ((gmask >> (e2 >> 3)) & 1u) ? sS2[wv_][e2] : 0.0f;
                if ((chosen >> e2) & 1ull) v = NEG_INF;
                if (v > best) { best = v; bi = e2; }
            }
            chosen |= 1ull << (unsigned)bi;
            rw[rr] = ((gmask >> (bi >> 3)) & 1u) ? sW2[wv_][bi] : 0.0f;
            ri[rr] = bi;
        }
        if (lane == 0) {
            const size_t obase = (size_t)tok * TOPK;
#pragma unroll
            for (int rr = 0; rr < TOPK; ++rr) {
                out_w[obase + rr] = rw[rr];
                out_i[obase + rr] = (float)ri[rr];
            }
        }
        __builtin_amdgcn_wave_barrier();   // keep sS2 stable until loop back
    }
}

extern "C" void kernel_launch(void* const* d_in, const int* in_sizes, int n_in,
                              void* d_out, int out_size, void* d_ws, size_t ws_size,
                              hipStream_t stream) {
    const float* x    = (const float*)d_in[0];
    const float* W    = (const float*)d_in[1];
    const float* b    = (const float*)d_in[2];
    const float* bias = (const float*)d_in[3];

    const int n = in_sizes[0] / DIM;   // 16384 tokens
    float* out_w = (float*)d_out;
    float* out_i = out_w + (size_t)n * TOPK;
    int*   wl    = (int*)d_ws;
    unsigned short* Wf = (unsigned short*)((char*)d_ws + WT_OFF);
    float* Wt    = (float*)((char*)d_ws + WT2_OFF);
    float* sSg   = (float*)((char*)d_ws + SG_OFF);

    prep_kernel<<<dim3((NEXP * DIM) / 256), dim3(256), 0, stream>>>(W, Wf, Wt, wl);
    gemm_kernel<<<dim3(n / 32), dim3(512), 0, stream>>>(x, Wf, b, bias, sSg);
    route_kernel<<<dim3(n / 128), dim3(256), 0, stream>>>(
        sSg, bias, out_w, out_i, wl);
    gate_fix_kernel<<<dim3(256), dim3(256), 0, stream>>>(
        x, Wt, b, bias, out_w, out_i, wl);
}

// Round 6
// 279.864 us; speedup vs baseline: 1.2179x; 1.1032x over previous
//
#include <hip/hip_runtime.h>
#include <math.h>

#define DIM   2048
#define NEXP  64
#define NGRP  8
#define GSIZE 8
#define TOPK  8
#define TOPKG 4

#define NKS   8              // K-slices per gemm block (one per wave)
#define KSL   (DIM / NKS)    // 256 k per slice
#define SMSTR 548            // 8*68+4 floats: bank-rotating k-slice stride

// margin thresholds (fp32 score scale). f16-split GEMM logit error:
// split residual + fp32 MFMA accum -> score 5-sigma ~1e-6. TAU ~20x that.
#define TAU_E 2e-5f
#define TAU_G 4e-5f
#define NEG_INF (-3.4e38f)
#define WLOFF  16
#define WT_OFF  (1 << 18)        // Wf (packed B-frags, 512 KB) at +256 KB
#define WT2_OFF (3 << 18)        // Wt (transposed fp32 W, 512 KB) at +768 KB
#define SG_OFF  (1 << 21)        // score table (4 MB) at +2 MB

typedef __attribute__((ext_vector_type(8)))  _Float16 f16x8;  // 8 f16 (4 VGPR)
typedef __attribute__((ext_vector_type(16))) float    f32x16; // 32x32 C/D

#define SB() __builtin_amdgcn_sched_barrier(0)

// ---- kernel 0: pack W into B-frag layout (hi/lo f16) + transposed fp32 ----
// B-frag for mfma_f32_32x32x16_f16: B[k][n], n = lane&31, k = (lane>>5)*8+j.
// Wf element index: (((h*2 + n2)*128 + kc)*64 + lane)*8 + j   (ushorts)
// Wt layout (for coalesced fix): float[((k>>2)*64 + e)*4 + (k&3)]
__global__ __launch_bounds__(256) void prep_kernel(
    const float* __restrict__ W, unsigned short* __restrict__ Wf,
    float* __restrict__ Wt, int* __restrict__ wl)
{
    const int g = blockIdx.x * 256 + threadIdx.x;   // 0..131071
    const int e = g >> 11, k = g & 2047;
    const float w = W[g];                            // W[e][k], coalesced
    const _Float16 hi = (_Float16)w;                 // RNE
    const _Float16 lo = (_Float16)(w - (float)hi);   // exact residual, RNE
    const int n2 = e >> 5, lcol = e & 31;
    const int kc = k >> 4, khalf = (k >> 3) & 1, j = k & 7;
    const int lane = (khalf << 5) | lcol;
    Wf[((((0 * 2 + n2) * 128 + kc) << 6) + lane) * 8 + j] =
        __builtin_bit_cast(unsigned short, hi);
    Wf[((((1 * 2 + n2) * 128 + kc) << 6) + lane) * 8 + j] =
        __builtin_bit_cast(unsigned short, lo);
    Wt[(((k >> 2) * 64 + e) << 2) + (k & 3)] = w;
    if (g < WLOFF) wl[g] = 0;
}

// ---- kernel 1: f16-split MFMA GEMM + merge + sigmoid -> score table -------
// Homogeneous prefetch pipeline (R4, verified <77us): per wave, ONE in-order
// VMEM stream (4 B-frag + 2 x loads per K-step), 2-slot register ring, fully
// unrolled 16 steps, CONSUME(t) then ISSUE(t+2), sched_barrier(0) pinned.
// Compiler's auto-wait becomes counted vmcnt(6); no barriers in the K-loop.
__global__ __launch_bounds__(512, 2) void gemm_kernel(
    const float* __restrict__ x,
    const unsigned short* __restrict__ Wf,
    const float* __restrict__ b,
    const float* __restrict__ bias,
    float* __restrict__ sSg)
{
    __shared__ float sM[NKS * SMSTR];    // 17.5 KB merge buffer

    const int tid  = threadIdx.x;
    const int ks   = tid >> 6;           // wave = K-slice 0..7
    const int lane = tid & 63;
    const int tok0 = blockIdx.x * 32;
    const int l31  = lane & 31, lh = lane >> 5;

    // A operand: A[row = lane&31][k-run = (lane>>5)*8 + j]
    const float* xr = x + (size_t)(tok0 + l31) * DIM + ks * KSL + lh * 8;
    const f16x8* Wfv = (const f16x8*)Wf;   // 16 B per element

    f32x16 acc0, acc1;
#pragma unroll
    for (int z = 0; z < 16; ++z) { acc0[z] = 0.f; acc1[z] = 0.f; }

    f16x8  Bq[2][4];
    float4 Xq[2][2];

#define ISSUE(t) do {                                                         \
        const int kc_ = ks * 16 + (t);                                        \
        Bq[(t) & 1][0] = Wfv[((0 * 2 + 0) * 128 + kc_) * 64 + lane];          \
        Bq[(t) & 1][1] = Wfv[((0 * 2 + 1) * 128 + kc_) * 64 + lane];          \
        Bq[(t) & 1][2] = Wfv[((1 * 2 + 0) * 128 + kc_) * 64 + lane];          \
        Bq[(t) & 1][3] = Wfv[((1 * 2 + 1) * 128 + kc_) * 64 + lane];          \
        Xq[(t) & 1][0] = *(const float4*)(xr + 16 * (t));                     \
        Xq[(t) & 1][1] = *(const float4*)(xr + 16 * (t) + 4);                 \
    } while (0)

    ISSUE(0); SB();
    ISSUE(1); SB();

#pragma unroll
    for (int t = 0; t < 16; ++t) {
        // CONSUME(t): auto-wait = counted vmcnt (next step's loads stay out)
        {
            const float4 qa = Xq[t & 1][0], qb = Xq[t & 1][1];
            const float xv[8] = {qa.x, qa.y, qa.z, qa.w, qb.x, qb.y, qb.z, qb.w};
            f16x8 ah, al;
#pragma unroll
            for (int j = 0; j < 8; j += 2) {
                const auto h2 = __builtin_amdgcn_cvt_pkrtz(xv[j], xv[j + 1]);
                const auto l2 = __builtin_amdgcn_cvt_pkrtz(xv[j]     - (float)h2.x,
                                                           xv[j + 1] - (float)h2.y);
                ah[j] = h2.x; ah[j + 1] = h2.y;
                al[j] = l2.x; al[j + 1] = l2.y;
            }
            acc0 = __builtin_amdgcn_mfma_f32_32x32x16_f16(ah, Bq[t & 1][0], acc0, 0, 0, 0);
            acc0 = __builtin_amdgcn_mfma_f32_32x32x16_f16(ah, Bq[t & 1][2], acc0, 0, 0, 0);
            acc0 = __builtin_amdgcn_mfma_f32_32x32x16_f16(al, Bq[t & 1][0], acc0, 0, 0, 0);
            acc1 = __builtin_amdgcn_mfma_f32_32x32x16_f16(ah, Bq[t & 1][1], acc1, 0, 0, 0);
            acc1 = __builtin_amdgcn_mfma_f32_32x32x16_f16(ah, Bq[t & 1][3], acc1, 0, 0, 0);
            acc1 = __builtin_amdgcn_mfma_f32_32x32x16_f16(al, Bq[t & 1][1], acc1, 0, 0, 0);
        }
        SB();
        if (t + 2 < 16) { ISSUE(t + 2); SB(); }
    }
#undef ISSUE

    // ---- merge 8 K-slice partials (4 rounds x 8 tokens), fused sigmoid ----
    // C/D layout (m74/m101-verified): col = lane&31,
    // row = (reg&3) + 8*(reg>>2) + 4*(lane>>5); reg = 4r+jj -> row = 8r+jj+4lh
#pragma unroll
    for (int r = 0; r < 4; ++r) {
#pragma unroll
        for (int jj = 0; jj < 4; ++jj) {
            const int t8 = jj + 4 * lh;                // row-in-round 0..7
            sM[ks * SMSTR + t8 * 68 + l31]      = acc0[4 * r + jj];
            sM[ks * SMSTR + t8 * 68 + l31 + 32] = acc1[4 * r + jj];
        }
        __syncthreads();
        {
            const int row = tid >> 6;                  // 0..7
            const int e   = tid & 63;
            float sum = 0.f;
#pragma unroll
            for (int s = 0; s < NKS; ++s)
                sum += sM[s * SMSTR + row * 68 + e];   // ordered, deterministic
            const float logit = sum + b[e];
            const float wv = 1.0f / (1.0f + expf(-logit));
            sSg[(size_t)(tok0 + 8 * r + row) * NEXP + e] = wv + bias[e];
        }
        __syncthreads();
    }
}

// ---- kernel 2: routing + margin flagging from score table ------------------
__global__ __launch_bounds__(256) void route_kernel(
    const float* __restrict__ sSg,
    const float* __restrict__ bias,
    float* __restrict__ out_w,
    float* __restrict__ out_i,
    int* __restrict__ wl)
{
    __shared__ float sT[128][65];        // 33.3 KB

    const int tid  = threadIdx.x;
    const int tok0 = blockIdx.x * 128;

    const float4* S4 = (const float4*)sSg + (size_t)tok0 * (NEXP / 4);
#pragma unroll
    for (int q = 0; q < 8; ++q) {
        const int idx = q * 256 + tid;           // 0..2047 float4s
        const int tk  = idx >> 4, c4 = idx & 15;
        const float4 v = S4[idx];
        sT[tk][c4 * 4 + 0] = v.x;
        sT[tk][c4 * 4 + 1] = v.y;
        sT[tk][c4 * 4 + 2] = v.z;
        sT[tk][c4 * 4 + 3] = v.w;
    }
    __syncthreads();

    if (tid < 128) {
        const int t = tid;

        float gs[NGRP];
#pragma unroll
        for (int g = 0; g < NGRP; ++g) {
            float m1 = NEG_INF, m2 = NEG_INF;
#pragma unroll
            for (int j = 0; j < GSIZE; ++j) {
                const float v = sT[t][g * GSIZE + j];
                if (v > m1) { m2 = m1; m1 = v; }
                else if (v > m2) { m2 = v; }
            }
            gs[g] = m1 + m2;
        }

        unsigned gmask = 0u;
        float g4val = NEG_INF;
        for (int rr = 0; rr < TOPKG; ++rr) {
            float best = NEG_INF; int bi = 0;
#pragma unroll
            for (int g = 0; g < NGRP; ++g) {
                const float v = ((gmask >> g) & 1u) ? NEG_INF : gs[g];
                if (v > best) { best = v; bi = g; }
            }
            gmask |= 1u << bi;
            g4val = best;
        }
        float m5 = NEG_INF;
#pragma unroll
        for (int g = 0; g < NGRP; ++g)
            if (!((gmask >> g) & 1u) && gs[g] > m5) m5 = gs[g];
        const float margin_g = g4val - m5;

        unsigned long long chosen = 0ull;
        const size_t obase = (size_t)(tok0 + t) * TOPK;
        float vals[TOPK + 1];
        for (int rr = 0; rr < TOPK + 1; ++rr) {
            float best = NEG_INF; int bi = 0;
            for (int e = 0; e < NEXP; ++e) {
                float v = ((gmask >> (e >> 3)) & 1u) ? sT[t][e] : 0.0f;
                if ((chosen >> e) & 1ull) v = NEG_INF;
                if (v > best) { best = v; bi = e; }
            }
            vals[rr] = best;
            if (rr < TOPK) {
                chosen |= 1ull << (unsigned)bi;
                out_w[obase + rr] = ((gmask >> (bi >> 3)) & 1u)
                                  ? (sT[t][bi] - bias[bi]) : 0.0f;
                out_i[obase + rr] = (float)bi;
            }
        }
        float margin_e = 1e30f;
#pragma unroll
        for (int rr = 0; rr < TOPK; ++rr) {
            const float d = vals[rr] - vals[rr + 1];
            if (d < margin_e) margin_e = d;
        }

        if (margin_g < TAU_G || margin_e < TAU_E) {
            const int slot = atomicAdd(wl, 1);
            wl[WLOFF + slot] = tok0 + t;
        }
    }
}

// ---- kernel 3: fp64 exact fixup, ONE BLOCK PER TOKEN, 4-wave K-split ------
// lane = expert; wave wv owns k-quarter [wv*512, wv*512+512). Wt4[k4*64+lane]
// -> 1 KB contiguous per instruction (L2-streaming); x row wave-uniform.
// unroll 8 -> 16 loads in flight per wave; fp64 partials reduced via LDS in
// fixed order (deterministic). ~6-8 us per token, tokens parallel per block.
__global__ __launch_bounds__(256) void gate_fix_kernel(
    const float* __restrict__ x,
    const float* __restrict__ Wt,
    const float* __restrict__ b,
    const float* __restrict__ bias,
    float* __restrict__ out_w,
    float* __restrict__ out_i,
    const int* __restrict__ wl)
{
    const int count = wl[0];

    __shared__ double sPart[4][NEXP];
    __shared__ float  sS2[NEXP], sW2[NEXP];

    const int tid  = threadIdx.x;
    const int wv_  = tid >> 6;           // wave = k-quarter 0..3
    const int lane = tid & 63;           // = expert

    const float4* Wt4 = (const float4*)Wt;

    for (int widx = blockIdx.x; widx < count; widx += (int)gridDim.x) {
        const int tok = wl[WLOFF + widx];
        const float4* xr4 = (const float4*)(x + (size_t)tok * DIM);

        double a0 = 0., a1 = 0., a2 = 0., a3 = 0.;
#pragma unroll 8
        for (int q = 0; q < DIM / 16; ++q) {     // 128 iters per wave
            const int k4 = wv_ * (DIM / 16) + q;
            const float4 wt = Wt4[(size_t)k4 * 64 + lane];
            const float4 xv = xr4[k4];
            a0 = fma((double)xv.x, (double)wt.x, a0);
            a1 = fma((double)xv.y, (double)wt.y, a1);
            a2 = fma((double)xv.z, (double)wt.z, a2);
            a3 = fma((double)xv.w, (double)wt.w, a3);
        }
        sPart[wv_][lane] = (a0 + a1) + (a2 + a3);
        __syncthreads();

        if (tid < NEXP) {
            const double logit = ((sPart[0][tid] + sPart[1][tid])
                                + (sPart[2][tid] + sPart[3][tid]))
                               + (double)b[tid];
            const float wvv = (float)(1.0 / (1.0 + exp(-logit)));
            sW2[tid] = wvv;
            sS2[tid] = wvv + bias[tid];
        }
        __syncthreads();

        if (tid == 0) {
            float gsv[NGRP];
#pragma unroll
            for (int g = 0; g < NGRP; ++g) {
                float m1 = NEG_INF, m2 = NEG_INF;
#pragma unroll
                for (int j = 0; j < GSIZE; ++j) {
                    const float v = sS2[g * GSIZE + j];
                    if (v > m1) { m2 = m1; m1 = v; }
                    else if (v > m2) { m2 = v; }
                }
                gsv[g] = m1 + m2;
            }
            unsigned gmask = 0u;
            for (int rr = 0; rr < TOPKG; ++rr) {
                float best = NEG_INF; int bi = 0;
#pragma unroll
                for (int g = 0; g < NGRP; ++g) {
                    const float v = ((gmask >> g) & 1u) ? NEG_INF : gsv[g];
                    if (v > best) { best = v; bi = g; }
                }
                gmask |= 1u << bi;
            }
            unsigned long long chosen = 0ull;
            const size_t obase = (size_t)tok * TOPK;
            for (int rr = 0; rr < TOPK; ++rr) {
                float best = NEG_INF; int bi = 0;
                for (int e2 = 0; e2 < NEXP; ++e2) {
                    float v = ((gmask >> (e2 >> 3)) & 1u) ? sS2[e2] : 0.0f;
                    if ((chosen >> e2) & 1ull) v = NEG_INF;
                    if (v > best) { best = v; bi = e2; }
                }
                chosen |= 1ull << (unsigned)bi;
                out_w[obase + rr] = ((gmask >> (bi >> 3)) & 1u) ? sW2[bi] : 0.0f;
                out_i[obase + rr] = (float)bi;
            }
        }
        __syncthreads();
    }
}

extern "C" void kernel_launch(void* const* d_in, const int* in_sizes, int n_in,
                              void* d_out, int out_size, void* d_ws, size_t ws_size,
                              hipStream_t stream) {
    const float* x    = (const float*)d_in[0];
    const float* W    = (const float*)d_in[1];
    const float* b    = (const float*)d_in[2];
    const float* bias = (const float*)d_in[3];

    const int n = in_sizes[0] / DIM;   // 16384 tokens
    float* out_w = (float*)d_out;
    float* out_i = out_w + (size_t)n * TOPK;
    int*   wl    = (int*)d_ws;
    unsigned short* Wf = (unsigned short*)((char*)d_ws + WT_OFF);
    float* Wt    = (float*)((char*)d_ws + WT2_OFF);
    float* sSg   = (float*)((char*)d_ws + SG_OFF);

    prep_kernel<<<dim3((NEXP * DIM) / 256), dim3(256), 0, stream>>>(W, Wf, Wt, wl);
    gemm_kernel<<<dim3(n / 32), dim3(512), 0, stream>>>(x, Wf, b, bias, sSg);
    route_kernel<<<dim3(n / 128), dim3(256), 0, stream>>>(
        sSg, bias, out_w, out_i, wl);
    gate_fix_kernel<<<dim3(256), dim3(256), 0, stream>>>(
        x, Wt, b, bias, out_w, out_i, wl);
}

// Round 7
// 277.260 us; speedup vs baseline: 1.2293x; 1.0094x over previous
//
#include <hip/hip_runtime.h>
#include <math.h>

#define DIM   2048
#define NEXP  64
#define NGRP  8
#define GSIZE 8
#define TOPK  8
#define TOPKG 4

#define NKS   8              // K-slices per gemm block (one per wave)
#define KSL   (DIM / NKS)    // 256 k per slice
#define SMSTR 548            // 8*68+4 floats: bank-rotating k-slice stride

// margin thresholds (fp32 score scale). f16-split GEMM logit error:
// split residual + fp32 MFMA accum -> score 5-sigma ~1e-6. TAU ~20x that.
#define TAU_E 2e-5f
#define TAU_G 4e-5f
#define NEG_INF (-3.4e38f)
#define WLOFF  16
#define WT_OFF  (1 << 18)        // Wf (packed B-frags, 512 KB) at +256 KB
#define WT2_OFF (3 << 18)        // Wt (transposed fp32 W, 512 KB) at +768 KB

typedef __attribute__((ext_vector_type(8)))  _Float16 f16x8;  // 8 f16 (4 VGPR)
typedef __attribute__((ext_vector_type(16))) float    f32x16; // 32x32 C/D

#define SB() __builtin_amdgcn_sched_barrier(0)

// ---- kernel 0: pack W into B-frag layout (hi/lo f16) + transposed fp32 ----
// B-frag for mfma_f32_32x32x16_f16: B[k][n], n = lane&31, k = (lane>>5)*8+j.
// Wf element index: (((h*2 + n2)*128 + kc)*64 + lane)*8 + j   (ushorts)
// Wt layout (for coalesced fix): float[((k>>2)*64 + e)*4 + (k&3)]
__global__ __launch_bounds__(256) void prep_kernel(
    const float* __restrict__ W, unsigned short* __restrict__ Wf,
    float* __restrict__ Wt, int* __restrict__ wl)
{
    const int g = blockIdx.x * 256 + threadIdx.x;   // 0..131071
    const int e = g >> 11, k = g & 2047;
    const float w = W[g];                            // W[e][k], coalesced
    const _Float16 hi = (_Float16)w;                 // RNE
    const _Float16 lo = (_Float16)(w - (float)hi);   // exact residual, RNE
    const int n2 = e >> 5, lcol = e & 31;
    const int kc = k >> 4, khalf = (k >> 3) & 1, j = k & 7;
    const int lane = (khalf << 5) | lcol;
    Wf[((((0 * 2 + n2) * 128 + kc) << 6) + lane) * 8 + j] =
        __builtin_bit_cast(unsigned short, hi);
    Wf[((((1 * 2 + n2) * 128 + kc) << 6) + lane) * 8 + j] =
        __builtin_bit_cast(unsigned short, lo);
    Wt[(((k >> 2) * 64 + e) << 2) + (k & 3)] = w;
    if (g < WLOFF) wl[g] = 0;
}

// ---- kernel 1: f16-split MFMA GEMM + merge + sigmoid + FUSED routing ------
// GEMM core: homogeneous prefetch pipeline (R4, verified): per wave, ONE
// in-order VMEM stream (4 B-frag + 2 x loads per K-step), 2-slot register
// ring, fully unrolled 16 steps, CONSUME(t) then ISSUE(t+2), sched_barrier
// pinned; compiler's auto-wait = counted vmcnt(6); no K-loop barriers.
// Merge writes scores to LDS sT[32][65]; threads 0-31 then run the routing
// + margin flagging in-block (identical logic/bits to the old route_kernel;
// the serial tail overlaps the other resident block's GEMM at 2 blocks/CU).
__global__ __launch_bounds__(512, 2) void gemm_kernel(
    const float* __restrict__ x,
    const unsigned short* __restrict__ Wf,
    const float* __restrict__ b,
    const float* __restrict__ bias,
    float* __restrict__ out_w,
    float* __restrict__ out_i,
    int* __restrict__ wl)
{
    __shared__ float sM[NKS * SMSTR];    // 17.5 KB merge buffer
    __shared__ float sT[32][65];         //  8.3 KB score table (this block)

    const int tid  = threadIdx.x;
    const int ks   = tid >> 6;           // wave = K-slice 0..7
    const int lane = tid & 63;
    const int tok0 = blockIdx.x * 32;
    const int l31  = lane & 31, lh = lane >> 5;

    // A operand: A[row = lane&31][k-run = (lane>>5)*8 + j]
    const float* xr = x + (size_t)(tok0 + l31) * DIM + ks * KSL + lh * 8;
    const f16x8* Wfv = (const f16x8*)Wf;   // 16 B per element

    f32x16 acc0, acc1;
#pragma unroll
    for (int z = 0; z < 16; ++z) { acc0[z] = 0.f; acc1[z] = 0.f; }

    f16x8  Bq[2][4];
    float4 Xq[2][2];

#define ISSUE(t) do {                                                         \
        const int kc_ = ks * 16 + (t);                                        \
        Bq[(t) & 1][0] = Wfv[((0 * 2 + 0) * 128 + kc_) * 64 + lane];          \
        Bq[(t) & 1][1] = Wfv[((0 * 2 + 1) * 128 + kc_) * 64 + lane];          \
        Bq[(t) & 1][2] = Wfv[((1 * 2 + 0) * 128 + kc_) * 64 + lane];          \
        Bq[(t) & 1][3] = Wfv[((1 * 2 + 1) * 128 + kc_) * 64 + lane];          \
        Xq[(t) & 1][0] = *(const float4*)(xr + 16 * (t));                     \
        Xq[(t) & 1][1] = *(const float4*)(xr + 16 * (t) + 4);                 \
    } while (0)

    ISSUE(0); SB();
    ISSUE(1); SB();

#pragma unroll
    for (int t = 0; t < 16; ++t) {
        // CONSUME(t): auto-wait = counted vmcnt (next step's loads stay out)
        {
            const float4 qa = Xq[t & 1][0], qb = Xq[t & 1][1];
            const float xv[8] = {qa.x, qa.y, qa.z, qa.w, qb.x, qb.y, qb.z, qb.w};
            f16x8 ah, al;
#pragma unroll
            for (int j = 0; j < 8; j += 2) {
                const auto h2 = __builtin_amdgcn_cvt_pkrtz(xv[j], xv[j + 1]);
                const auto l2 = __builtin_amdgcn_cvt_pkrtz(xv[j]     - (float)h2.x,
                                                           xv[j + 1] - (float)h2.y);
                ah[j] = h2.x; ah[j + 1] = h2.y;
                al[j] = l2.x; al[j + 1] = l2.y;
            }
            acc0 = __builtin_amdgcn_mfma_f32_32x32x16_f16(ah, Bq[t & 1][0], acc0, 0, 0, 0);
            acc0 = __builtin_amdgcn_mfma_f32_32x32x16_f16(ah, Bq[t & 1][2], acc0, 0, 0, 0);
            acc0 = __builtin_amdgcn_mfma_f32_32x32x16_f16(al, Bq[t & 1][0], acc0, 0, 0, 0);
            acc1 = __builtin_amdgcn_mfma_f32_32x32x16_f16(ah, Bq[t & 1][1], acc1, 0, 0, 0);
            acc1 = __builtin_amdgcn_mfma_f32_32x32x16_f16(ah, Bq[t & 1][3], acc1, 0, 0, 0);
            acc1 = __builtin_amdgcn_mfma_f32_32x32x16_f16(al, Bq[t & 1][1], acc1, 0, 0, 0);
        }
        SB();
        if (t + 2 < 16) { ISSUE(t + 2); SB(); }
    }
#undef ISSUE

    // ---- merge 8 K-slice partials (4 rounds x 8 tokens), fused sigmoid ----
    // C/D layout (m74/m101-verified): col = lane&31,
    // row = (reg&3) + 8*(reg>>2) + 4*(lane>>5); reg = 4r+jj -> row = 8r+jj+4lh
#pragma unroll
    for (int r = 0; r < 4; ++r) {
#pragma unroll
        for (int jj = 0; jj < 4; ++jj) {
            const int t8 = jj + 4 * lh;                // row-in-round 0..7
            sM[ks * SMSTR + t8 * 68 + l31]      = acc0[4 * r + jj];
            sM[ks * SMSTR + t8 * 68 + l31 + 32] = acc1[4 * r + jj];
        }
        __syncthreads();
        {
            const int row = tid >> 6;                  // 0..7
            const int e   = tid & 63;
            float sum = 0.f;
#pragma unroll
            for (int s = 0; s < NKS; ++s)
                sum += sM[s * SMSTR + row * 68 + e];   // ordered, deterministic
            const float logit = sum + b[e];
            const float wv = 1.0f / (1.0f + expf(-logit));
            sT[8 * r + row][e] = wv + bias[e];
        }
        __syncthreads();
    }

    // ---- fused routing + margin flagging: thread t per token (t < 32) ----
    if (tid < 32) {
        const int t = tid;

        float gs[NGRP];
#pragma unroll
        for (int g = 0; g < NGRP; ++g) {
            float m1 = NEG_INF, m2 = NEG_INF;
#pragma unroll
            for (int j = 0; j < GSIZE; ++j) {
                const float v = sT[t][g * GSIZE + j];
                if (v > m1) { m2 = m1; m1 = v; }
                else if (v > m2) { m2 = v; }
            }
            gs[g] = m1 + m2;
        }

        unsigned gmask = 0u;
        float g4val = NEG_INF;
        for (int rr = 0; rr < TOPKG; ++rr) {
            float best = NEG_INF; int bi = 0;
#pragma unroll
            for (int g = 0; g < NGRP; ++g) {
                const float v = ((gmask >> g) & 1u) ? NEG_INF : gs[g];
                if (v > best) { best = v; bi = g; }
            }
            gmask |= 1u << bi;
            g4val = best;
        }
        float m5 = NEG_INF;
#pragma unroll
        for (int g = 0; g < NGRP; ++g)
            if (!((gmask >> g) & 1u) && gs[g] > m5) m5 = gs[g];
        const float margin_g = g4val - m5;

        unsigned long long chosen = 0ull;
        const size_t obase = (size_t)(tok0 + t) * TOPK;
        float vals[TOPK + 1];
        for (int rr = 0; rr < TOPK + 1; ++rr) {
            float best = NEG_INF; int bi = 0;
            for (int e = 0; e < NEXP; ++e) {
                float v = ((gmask >> (e >> 3)) & 1u) ? sT[t][e] : 0.0f;
                if ((chosen >> e) & 1ull) v = NEG_INF;
                if (v > best) { best = v; bi = e; }
            }
            vals[rr] = best;
            if (rr < TOPK) {
                chosen |= 1ull << (unsigned)bi;
                out_w[obase + rr] = ((gmask >> (bi >> 3)) & 1u)
                                  ? (sT[t][bi] - bias[bi]) : 0.0f;
                out_i[obase + rr] = (float)bi;
            }
        }
        float margin_e = 1e30f;
#pragma unroll
        for (int rr = 0; rr < TOPK; ++rr) {
            const float d = vals[rr] - vals[rr + 1];
            if (d < margin_e) margin_e = d;
        }

        if (margin_g < TAU_G || margin_e < TAU_E) {
            const int slot = atomicAdd(wl, 1);
            wl[WLOFF + slot] = tok0 + t;
        }
    }
}

// ---- kernel 2: fp64 exact fixup, ONE BLOCK PER TOKEN, 4-wave K-split ------
// lane = expert; wave wv owns k-quarter [wv*512, wv*512+512). Wt4[k4*64+lane]
// -> 1 KB contiguous per instruction (L2-streaming); x row wave-uniform.
// unroll 8 -> 16 loads in flight per wave; fp64 partials reduced via LDS in
// fixed order (deterministic). ~6-8 us per token, tokens parallel per block.
__global__ __launch_bounds__(256) void gate_fix_kernel(
    const float* __restrict__ x,
    const float* __restrict__ Wt,
    const float* __restrict__ b,
    const float* __restrict__ bias,
    float* __restrict__ out_w,
    float* __restrict__ out_i,
    const int* __restrict__ wl)
{
    const int count = wl[0];

    __shared__ double sPart[4][NEXP];
    __shared__ float  sS2[NEXP], sW2[NEXP];

    const int tid  = threadIdx.x;
    const int wv_  = tid >> 6;           // wave = k-quarter 0..3
    const int lane = tid & 63;           // = expert

    const float4* Wt4 = (const float4*)Wt;

    for (int widx = blockIdx.x; widx < count; widx += (int)gridDim.x) {
        const int tok = wl[WLOFF + widx];
        const float4* xr4 = (const float4*)(x + (size_t)tok * DIM);

        double a0 = 0., a1 = 0., a2 = 0., a3 = 0.;
#pragma unroll 8
        for (int q = 0; q < DIM / 16; ++q) {     // 128 iters per wave
            const int k4 = wv_ * (DIM / 16) + q;
            const float4 wt = Wt4[(size_t)k4 * 64 + lane];
            const float4 xv = xr4[k4];
            a0 = fma((double)xv.x, (double)wt.x, a0);
            a1 = fma((double)xv.y, (double)wt.y, a1);
            a2 = fma((double)xv.z, (double)wt.z, a2);
            a3 = fma((double)xv.w, (double)wt.w, a3);
        }
        sPart[wv_][lane] = (a0 + a1) + (a2 + a3);
        __syncthreads();

        if (tid < NEXP) {
            const double logit = ((sPart[0][tid] + sPart[1][tid])
                                + (sPart[2][tid] + sPart[3][tid]))
                               + (double)b[tid];
            const float wvv = (float)(1.0 / (1.0 + exp(-logit)));
            sW2[tid] = wvv;
            sS2[tid] = wvv + bias[tid];
        }
        __syncthreads();

        if (tid == 0) {
            float gsv[NGRP];
#pragma unroll
            for (int g = 0; g < NGRP; ++g) {
                float m1 = NEG_INF, m2 = NEG_INF;
#pragma unroll
                for (int j = 0; j < GSIZE; ++j) {
                    const float v = sS2[g * GSIZE + j];
                    if (v > m1) { m2 = m1; m1 = v; }
                    else if (v > m2) { m2 = v; }
                }
                gsv[g] = m1 + m2;
            }
            unsigned gmask = 0u;
            for (int rr = 0; rr < TOPKG; ++rr) {
                float best = NEG_INF; int bi = 0;
#pragma unroll
                for (int g = 0; g < NGRP; ++g) {
                    const float v = ((gmask >> g) & 1u) ? NEG_INF : gsv[g];
                    if (v > best) { best = v; bi = g; }
                }
                gmask |= 1u << bi;
            }
            unsigned long long chosen = 0ull;
            const size_t obase = (size_t)tok * TOPK;
            for (int rr = 0; rr < TOPK; ++rr) {
                float best = NEG_INF; int bi = 0;
                for (int e2 = 0; e2 < NEXP; ++e2) {
                    float v = ((gmask >> (e2 >> 3)) & 1u) ? sS2[e2] : 0.0f;
                    if ((chosen >> e2) & 1ull) v = NEG_INF;
                    if (v > best) { best = v; bi = e2; }
                }
                chosen |= 1ull << (unsigned)bi;
                out_w[obase + rr] = ((gmask >> (bi >> 3)) & 1u) ? sW2[bi] : 0.0f;
                out_i[obase + rr] = (float)bi;
            }
        }
        __syncthreads();
    }
}

extern "C" void kernel_launch(void* const* d_in, const int* in_sizes, int n_in,
                              void* d_out, int out_size, void* d_ws, size_t ws_size,
                              hipStream_t stream) {
    const float* x    = (const float*)d_in[0];
    const float* W    = (const float*)d_in[1];
    const float* b    = (const float*)d_in[2];
    const float* bias = (const float*)d_in[3];

    const int n = in_sizes[0] / DIM;   // 16384 tokens
    float* out_w = (float*)d_out;
    float* out_i = out_w + (size_t)n * TOPK;
    int*   wl    = (int*)d_ws;
    unsigned short* Wf = (unsigned short*)((char*)d_ws + WT_OFF);
    float* Wt    = (float*)((char*)d_ws + WT2_OFF);

    prep_kernel<<<dim3((NEXP * DIM) / 256), dim3(256), 0, stream>>>(W, Wf, Wt, wl);
    gemm_kernel<<<dim3(n / 32), dim3(512), 0, stream>>>(
        x, Wf, b, bias, out_w, out_i, wl);
    gate_fix_kernel<<<dim3(256), dim3(256), 0, stream>>>(
        x, Wt, b, bias, out_w, out_i, wl);
}